// Round 2
// baseline (101730.383 us; speedup 1.0000x reference)
//
#include <hip/hip_runtime.h>
#include <math.h>

// ---------------------------------------------------------------------------
// BiLSTM-CRF tagger on MI355X.
//   T=2048, D=512, H=512, HD=256, L=2, NTAGS=20, START=18, END=19
//
// R1-R6 history: 8-WG split with cross-XCD h-exchange. Best (R6, L2-RMW
// seqlock) = 3.45ms/recur, ~4050cy/step of which ~3800cy is communication.
// R7: the per-step compute is only 262144 MACs = 2048 VALU-cycles on ONE CU
// (128 FMA lanes/cy). That is LESS than the measured comm overhead of any
// multi-WG scheme tried. So: single 1024-thread WG per direction, h in LDS,
// __syncthreads-only sync. Weights stay in registers (64 VGPR/thread).
// Per-step: 16x ds_read_b128 (4-way k-slice, padded -> conflict-free,
// broadcast) + 256 v_fmac + 2-level quad shfl reduce + gates on 4 waves.
// Model: ~2700cy/step -> ~2.3ms/recur (from 3.45).
// R8: R7 bench died to an infra failure (container acquisition), zero
// counters returned. Kernel unchanged — re-measure.
// ---------------------------------------------------------------------------

#define T_LEN 2048
#define DMODEL 512
#define HD 256
#define NTAGS 20
#define START_TAG 18
#define END_TAG 19

__device__ __forceinline__ float fsig(float x) {
  return 1.0f / (1.0f + __expf(-x));
}
__device__ __forceinline__ float ftanh(float x) {
  float xc = fminf(15.0f, fmaxf(-15.0f, x));
  float e = __expf(2.0f * xc);
  return (e - 1.0f) / (e + 1.0f);
}

// ---------------------------------------------------------------------------
// 1. Embedding gather: x0[t][:] = emb[sentence[t]][:]
// ---------------------------------------------------------------------------
__global__ void embed_k(const int* __restrict__ sent,
                        const float* __restrict__ emb,
                        float* __restrict__ x0) {
  int t = blockIdx.x;
  int tid = threadIdx.x;  // 0..127
  int tok = sent[t];
  const float4* src = (const float4*)(emb + (size_t)tok * DMODEL);
  float4* dst = (float4*)(x0 + (size_t)t * DMODEL);
  dst[tid] = src[tid];
}

// ---------------------------------------------------------------------------
// 2. xg GEMM: out[t][n] = sum_k X[t][k] * W[n][k] + b[n]
//    X: [2048][512], W: [1024][512], out: [2048][1024]
// 128x128 block tile, 8x8 per thread, k-tile 16.
// grid: (N/128=8, M/128=16, 2 dirs), block 256
// ---------------------------------------------------------------------------
__global__ __launch_bounds__(256) void gemm_xg_k(
    const float* __restrict__ X,
    const float* __restrict__ Wf, const float* __restrict__ Wb,
    const float* __restrict__ bf, const float* __restrict__ bb,
    float* __restrict__ outf, float* __restrict__ outb) {
  int bx = blockIdx.x;   // N tile (0..7)
  int by = blockIdx.y;   // M tile (0..15)
  int dir = blockIdx.z;
  const float* W = dir ? Wb : Wf;
  const float* bias = dir ? bb : bf;
  float* out = dir ? outb : outf;

  __shared__ __align__(16) float Xs[16][132];
  __shared__ __align__(16) float Ws[16][132];

  int tid = threadIdx.x;
  int tx = tid & 15;   // 0..15 -> N
  int ty = tid >> 4;   // 0..15 -> M

  float acc[8][8];
#pragma unroll
  for (int i = 0; i < 8; i++)
#pragma unroll
    for (int j = 0; j < 8; j++) acc[i][j] = 0.0f;

  for (int kt = 0; kt < DMODEL / 16; kt++) {
    __syncthreads();
#pragma unroll
    for (int l = 0; l < 2; l++) {
      int fi = tid + l * 256;        // 0..511  (128 rows x 4 float4)
      int row = fi >> 2;
      int kq = fi & 3;
      float4 xv = *(const float4*)(X + (size_t)(by * 128 + row) * DMODEL + kt * 16 + kq * 4);
      Xs[kq * 4 + 0][row] = xv.x;
      Xs[kq * 4 + 1][row] = xv.y;
      Xs[kq * 4 + 2][row] = xv.z;
      Xs[kq * 4 + 3][row] = xv.w;
      float4 wv = *(const float4*)(W + (size_t)(bx * 128 + row) * DMODEL + kt * 16 + kq * 4);
      Ws[kq * 4 + 0][row] = wv.x;
      Ws[kq * 4 + 1][row] = wv.y;
      Ws[kq * 4 + 2][row] = wv.z;
      Ws[kq * 4 + 3][row] = wv.w;
    }
    __syncthreads();
#pragma unroll
    for (int k = 0; k < 16; k++) {
      float4 a0 = *(const float4*)&Xs[k][ty * 4];
      float4 a1 = *(const float4*)&Xs[k][64 + ty * 4];
      float4 b0 = *(const float4*)&Ws[k][tx * 4];
      float4 b1 = *(const float4*)&Ws[k][64 + tx * 4];
      float a[8] = {a0.x, a0.y, a0.z, a0.w, a1.x, a1.y, a1.z, a1.w};
      float b[8] = {b0.x, b0.y, b0.z, b0.w, b1.x, b1.y, b1.z, b1.w};
#pragma unroll
      for (int i = 0; i < 8; i++)
#pragma unroll
        for (int j = 0; j < 8; j++) acc[i][j] += a[i] * b[j];
    }
  }

  float4 bv0 = *(const float4*)(bias + bx * 128 + tx * 4);
  float4 bv1 = *(const float4*)(bias + bx * 128 + 64 + tx * 4);
  float bb8[8] = {bv0.x, bv0.y, bv0.z, bv0.w, bv1.x, bv1.y, bv1.z, bv1.w};
#pragma unroll
  for (int i = 0; i < 8; i++) {
    int row = by * 128 + ((i < 4) ? (ty * 4 + i) : (64 + ty * 4 + (i - 4)));
    float4 o0 = {acc[i][0] + bb8[0], acc[i][1] + bb8[1], acc[i][2] + bb8[2], acc[i][3] + bb8[3]};
    float4 o1 = {acc[i][4] + bb8[4], acc[i][5] + bb8[5], acc[i][6] + bb8[6], acc[i][7] + bb8[7]};
    *(float4*)(out + (size_t)row * 1024 + bx * 128 + tx * 4) = o0;
    *(float4*)(out + (size_t)row * 1024 + bx * 128 + 64 + tx * 4) = o1;
  }
}

// ---------------------------------------------------------------------------
// 3/5. Recurrence: ONE workgroup (1024 threads, 16 waves) per direction.
// grid: (2 dirs), block 1024. No inter-WG communication at all.
//
// Work layout (per thread):
//   w  = tid>>6 (wave), lane = tid&63, s = lane&3 (k-slice), rg = lane>>2
//   quad (lanes 4rg..4rg+3 of wave w) computes rows r_i = w*64 + rg + 16*i,
//   i=0..3; thread holds Whh[r_i][64s .. 64s+64) = 64 float4 = 64 VGPRs.
//   Per step: read its 64-float h-slice (16x ds_read_b128, reused over the
//   4 rows), 256 v_fmac, 2-level shfl_xor over the quad -> full z for the
//   4 rows in every quad lane; lane s writes row r_s (+xg prefetch +bias).
//   Then waves 0..3 (tid<256) do the gates for cell tid, write h back to
//   the padded LDS slices and stream it to xnext.
//
// LDS bank math: slice s base = s*68 floats -> bank offset 4s; for read j
// the 4 address streams hit banks {4j..4j+3}+{0,4,8,12} mod 32: disjoint,
// conflict-free broadcast (16 lanes/address).
// ---------------------------------------------------------------------------
__global__ __launch_bounds__(1024, 4) void recur_k(
    const float* __restrict__ xg_f, const float* __restrict__ xg_b,
    const float* __restrict__ Whh_f, const float* __restrict__ Whh_b,
    const float* __restrict__ bhh_f, const float* __restrict__ bhh_b,
    float* __restrict__ xnext) {
  const int dir = blockIdx.x;
  const int tid = threadIdx.x;
  const int w = tid >> 6;      // wave 0..15
  const int lane = tid & 63;
  const int s = lane & 3;      // k-slice 0..3 (64 h values each)
  const int rg = lane >> 2;    // row-group 0..15
  const int rbase = w * 64 + rg;
  const int myrow = rbase + 16 * s;  // the row this thread owns for z/xg

  const float* __restrict__ Whh = dir ? Whh_b : Whh_f;
  const float* __restrict__ bhh = dir ? bhh_b : bhh_f;
  const float* __restrict__ xg = dir ? xg_b : xg_f;

  // 256 weights/thread, fully static indexing -> registers.
  float4 Wv[4][16];
#pragma unroll
  for (int i = 0; i < 4; i++) {
    const float4* wr =
        (const float4*)(Whh + (size_t)(rbase + 16 * i) * HD + s * 64);
#pragma unroll
    for (int j = 0; j < 16; j++) Wv[i][j] = wr[j];
  }
  const float bias = bhh[myrow];

  __shared__ __align__(16) float hbuf[4 * 68];  // 4 padded 64-float slices
  __shared__ float zbuf[1024];
  if (tid < 4 * 68) hbuf[tid] = 0.0f;
  __syncthreads();

  const float4* hs4 = (const float4*)(hbuf + s * 68);
  float c = 0.0f;  // cell state (tid < 256 only)

#pragma unroll 1
  for (int it = 0; it < T_LEN; ++it) {
    const int t = dir ? (T_LEN - 1 - it) : it;
    // prefetch input-gate contribution for the owned row (hidden under FMA)
    float xgv = xg[(size_t)t * 1024 + myrow];

    float4 a0 = {0.f, 0.f, 0.f, 0.f};
    float4 a1 = {0.f, 0.f, 0.f, 0.f};
    float4 a2 = {0.f, 0.f, 0.f, 0.f};
    float4 a3 = {0.f, 0.f, 0.f, 0.f};
#pragma unroll
    for (int j = 0; j < 16; j++) {
      float4 hv = hs4[j];
      a0.x += Wv[0][j].x * hv.x; a0.y += Wv[0][j].y * hv.y;
      a0.z += Wv[0][j].z * hv.z; a0.w += Wv[0][j].w * hv.w;
      a1.x += Wv[1][j].x * hv.x; a1.y += Wv[1][j].y * hv.y;
      a1.z += Wv[1][j].z * hv.z; a1.w += Wv[1][j].w * hv.w;
      a2.x += Wv[2][j].x * hv.x; a2.y += Wv[2][j].y * hv.y;
      a2.z += Wv[2][j].z * hv.z; a2.w += Wv[2][j].w * hv.w;
      a3.x += Wv[3][j].x * hv.x; a3.y += Wv[3][j].y * hv.y;
      a3.z += Wv[3][j].z * hv.z; a3.w += Wv[3][j].w * hv.w;
    }
    float p0 = (a0.x + a0.y) + (a0.z + a0.w);
    float p1 = (a1.x + a1.y) + (a1.z + a1.w);
    float p2 = (a2.x + a2.y) + (a2.z + a2.w);
    float p3 = (a3.x + a3.y) + (a3.z + a3.w);
    // combine the 4 k-slices within each lane quad
    p0 += __shfl_xor(p0, 1); p0 += __shfl_xor(p0, 2);
    p1 += __shfl_xor(p1, 1); p1 += __shfl_xor(p1, 2);
    p2 += __shfl_xor(p2, 1); p2 += __shfl_xor(p2, 2);
    p3 += __shfl_xor(p3, 1); p3 += __shfl_xor(p3, 2);
    float zm = (s == 0) ? p0 : (s == 1) ? p1 : (s == 2) ? p2 : p3;
    zbuf[myrow] = zm + xgv + bias;
    __syncthreads();  // zbuf complete; hbuf reads of h_{t-1} done

    if (tid < HD) {   // waves 0..3 -> one per SIMD
      float zi = zbuf[tid];
      float zf = zbuf[256 + tid];
      float zg = zbuf[512 + tid];
      float zo = zbuf[768 + tid];
      c = fsig(zf) * c + fsig(zi) * ftanh(zg);
      float h = fsig(zo) * ftanh(c);
      hbuf[((tid >> 6) * 68) + (tid & 63)] = h;  // padded slice layout
      xnext[(size_t)t * DMODEL + dir * HD + tid] = h;
    }
    __syncthreads();  // h_t visible to all waves
  }
}

// ---------------------------------------------------------------------------
// 6. Projection: feats[t][n] = x2[t][:] . W_out[n][:] + b_out[n]
// ---------------------------------------------------------------------------
__global__ void proj_k(const float* __restrict__ x2,
                       const float* __restrict__ Wo,
                       const float* __restrict__ bo,
                       float* __restrict__ feats) {
  int t = blockIdx.x;
  int tid = threadIdx.x;
  int n = tid & 31;
  int seg = tid >> 5;   // 0..7
  __shared__ float red[8][32];
  float s = 0.0f;
  if (n < NTAGS) {
    const float* xr = x2 + (size_t)t * DMODEL + seg * 64;
    const float* wr = Wo + (size_t)n * DMODEL + seg * 64;
#pragma unroll
    for (int j = 0; j < 64; j++) s += xr[j] * wr[j];
  }
  red[seg][n] = s;
  __syncthreads();
  if (tid < NTAGS) {
    float tot = bo[tid];
#pragma unroll
    for (int k = 0; k < 8; k++) tot += red[k][tid];
    feats[(size_t)t * NTAGS + tid] = tot;
  }
}

// ---------------------------------------------------------------------------
// 7. Viterbi: single block, 64 threads (one wave).
// ---------------------------------------------------------------------------
__global__ void viterbi_k(const float* __restrict__ feats,
                          const float* __restrict__ tr,
                          float* __restrict__ out) {
  __shared__ float v[NTAGS];
  __shared__ unsigned char bp[T_LEN * NTAGS];  // 40KB
  __shared__ float term[NTAGS];
  int tid = threadIdx.x;

  float trrow[NTAGS];
  if (tid < NTAGS) {
#pragma unroll
    for (int p = 0; p < NTAGS; p++) trrow[p] = tr[tid * NTAGS + p];
    v[tid] = (tid == START_TAG) ? 0.0f : -10000.0f;
  }
  __syncthreads();

#pragma unroll 1
  for (int t = 0; t < T_LEN; t++) {
    float fv = 0.0f;
    if (tid < NTAGS) fv = feats[(size_t)t * NTAGS + tid];
    float best = -3.4e38f;
    int arg = 0;
    if (tid < NTAGS) {
#pragma unroll
      for (int p = 0; p < NTAGS; p++) {
        float sc = v[p] + trrow[p];
        if (sc > best) { best = sc; arg = p; }
      }
      bp[t * NTAGS + tid] = (unsigned char)arg;
    }
    __syncthreads();
    if (tid < NTAGS) v[tid] = best + fv;
    __syncthreads();
  }

  if (tid < NTAGS) term[tid] = v[tid] + tr[END_TAG * NTAGS + tid];
  __syncthreads();
  if (tid == 0) {
    float bs = term[0];
    int bi = 0;
    for (int p = 1; p < NTAGS; p++) {
      if (term[p] > bs) { bs = term[p]; bi = p; }
    }
    out[0] = bs;
    int tag = bi;
    for (int t = T_LEN - 1; t >= 0; t--) {
      out[1 + t] = (float)tag;
      tag = bp[t * NTAGS + tag];
    }
  }
}

// ---------------------------------------------------------------------------
// Launch
// ---------------------------------------------------------------------------
extern "C" void kernel_launch(void* const* d_in, const int* in_sizes, int n_in,
                              void* d_out, int out_size, void* d_ws, size_t ws_size,
                              hipStream_t stream) {
  const int* sent = (const int*)d_in[0];
  const float* emb = (const float*)d_in[1];
  const float* l0f_Wih = (const float*)d_in[2];
  const float* l0f_Whh = (const float*)d_in[3];
  const float* l0f_bih = (const float*)d_in[4];
  const float* l0f_bhh = (const float*)d_in[5];
  const float* l0b_Wih = (const float*)d_in[6];
  const float* l0b_Whh = (const float*)d_in[7];
  const float* l0b_bih = (const float*)d_in[8];
  const float* l0b_bhh = (const float*)d_in[9];
  const float* l1f_Wih = (const float*)d_in[10];
  const float* l1f_Whh = (const float*)d_in[11];
  const float* l1f_bih = (const float*)d_in[12];
  const float* l1f_bhh = (const float*)d_in[13];
  const float* l1b_Wih = (const float*)d_in[14];
  const float* l1b_Whh = (const float*)d_in[15];
  const float* l1b_bih = (const float*)d_in[16];
  const float* l1b_bhh = (const float*)d_in[17];
  const float* W_out = (const float*)d_in[18];
  const float* b_out = (const float*)d_in[19];
  const float* transitions = (const float*)d_in[20];

  char* ws = (char*)d_ws;
  size_t off = 0;
  float* x0 = (float*)(ws + off);  off += (size_t)T_LEN * DMODEL * 4;          // 4MB
  float* xgf = (float*)(ws + off); off += (size_t)T_LEN * 1024 * 4;            // 8MB
  float* xgb = (float*)(ws + off); off += (size_t)T_LEN * 1024 * 4;            // 8MB
  float* x1 = (float*)(ws + off);  off += (size_t)T_LEN * DMODEL * 4;          // 4MB
  float* x2 = (float*)(ws + off);  off += (size_t)T_LEN * DMODEL * 4;          // 4MB
  float* feats = (float*)(ws + off); off += (size_t)T_LEN * NTAGS * 4;

  float* outf = (float*)d_out;

  embed_k<<<dim3(T_LEN), dim3(128), 0, stream>>>(sent, emb, x0);

  gemm_xg_k<<<dim3(8, 16, 2), dim3(256), 0, stream>>>(
      x0, l0f_Wih, l0b_Wih, l0f_bih, l0b_bih, xgf, xgb);

  recur_k<<<dim3(2), dim3(1024), 0, stream>>>(
      xgf, xgb, l0f_Whh, l0b_Whh, l0f_bhh, l0b_bhh, x1);

  gemm_xg_k<<<dim3(8, 16, 2), dim3(256), 0, stream>>>(
      x1, l1f_Wih, l1b_Wih, l1f_bih, l1b_bih, xgf, xgb);

  recur_k<<<dim3(2), dim3(1024), 0, stream>>>(
      xgf, xgb, l1f_Whh, l1b_Whh, l1f_bhh, l1b_bhh, x2);

  proj_k<<<dim3(T_LEN), dim3(256), 0, stream>>>(x2, W_out, b_out, feats);

  viterbi_k<<<dim3(1), dim3(64), 0, stream>>>(feats, transitions, outf);
}

// Round 3
// 7823.551 us; speedup vs baseline: 13.0031x; 13.0031x over previous
//
#include <hip/hip_runtime.h>
#include <math.h>

// ---------------------------------------------------------------------------
// BiLSTM-CRF tagger on MI355X.
//   T=2048, D=512, H=512, HD=256, L=2, NTAGS=20, START=18, END=19
//
// R1: 4096 spinning agent-acquire loads -> 7.3ms recur (cache-inv storm).
// R3: release/acquire slots -> 6.2ms: agent fence protocol (L2 wb+inv) is
//     the per-step cost on non-coherent XCDs.
// R4: fence-free seqlock (tag<<32|payload in one relaxed 64b agent atomic),
//     parity double-buffer -> 3.58ms.
// R5: sc0-load seqlock on a same-XCD octet -> HANG (sc0 load can be served
//     from consumer's own L1 -> stale spin forever).
// R6: L2-read primitive: atomic RMW w/ return executes AT the XCD L2.
//     Runtime coherence probe elects an octet; fallback = R4 seqlock.
//     3.45ms/recur @ VGPR_Count=84.
// R7: single 1024-thr WG/dir, "weights in registers". FATAL ARITHMETIC BUG:
//     Wv[4][16] float4 = 256 VGPRs vs cap 128 -> full spill to scratch ->
//     90ms/recur. Lesson: 1 CU's VGPR file (128K floats) < Whh (256K floats);
//     single-CU register residency is impossible. ALSO exposes that R6's
//     VGPR_Count=84 < 128 needed => R6 was *partially spilling* Wv too;
//     a chunk of its 4050cy/step was scratch reloads, not comm.
// R8 (this): R6 verbatim + __launch_bounds__(256, 1) on recur_k. 256-thr WG
//     = 4 waves = 1 wave/SIMD -> VGPR cap 512; Wv[32] (128 VGPRs) + temps
//     now truly resident. Predict step 4050 -> ~2100-2500cy.
// ---------------------------------------------------------------------------

#define T_LEN 2048
#define DMODEL 512
#define HD 256
#define NTAGS 20
#define START_TAG 18
#define END_TAG 19
#define NCAND 128   // candidate WGs per direction for the election

__device__ __forceinline__ float fsig(float x) {
  return 1.0f / (1.0f + __expf(-x));
}
__device__ __forceinline__ float ftanh(float x) {
  float xc = fminf(15.0f, fmaxf(-15.0f, x));
  float e = __expf(2.0f * xc);
  return (e - 1.0f) / (e + 1.0f);
}

// Read current L2 content (bypasses L1 by construction: atomic RMW executes
// at the coherence point). sc0 = return old value on gfx950.
__device__ __forceinline__ unsigned long long rd_l2(unsigned long long* p) {
  unsigned long long old;
  unsigned long long zero = 0;
  asm volatile("global_atomic_add_x2 %0, %1, %2, off sc0\n\ts_waitcnt vmcnt(0)"
               : "=&v"(old)
               : "v"(p), "v"(zero)
               : "memory");
  return old;
}
// Producer publish: plain store; CDNA L1 is write-through so this reaches the
// XCD-shared L2 without any cache-maintenance ops.
__device__ __forceinline__ void pub_l2(unsigned long long* p,
                                       unsigned long long v) {
  *(volatile unsigned long long*)p = v;
}

// ---------------------------------------------------------------------------
// 1. Embedding gather: x0[t][:] = emb[sentence[t]][:]
// ---------------------------------------------------------------------------
__global__ void embed_k(const int* __restrict__ sent,
                        const float* __restrict__ emb,
                        float* __restrict__ x0) {
  int t = blockIdx.x;
  int tid = threadIdx.x;  // 0..127
  int tok = sent[t];
  const float4* src = (const float4*)(emb + (size_t)tok * DMODEL);
  float4* dst = (float4*)(x0 + (size_t)t * DMODEL);
  dst[tid] = src[tid];
}

// ---------------------------------------------------------------------------
// 2. xg GEMM: out[t][n] = sum_k X[t][k] * W[n][k] + b[n]
//    X: [2048][512], W: [1024][512], out: [2048][1024]
// 128x128 block tile, 8x8 per thread, k-tile 16.
// grid: (N/128=8, M/128=16, 2 dirs), block 256
// ---------------------------------------------------------------------------
__global__ __launch_bounds__(256) void gemm_xg_k(
    const float* __restrict__ X,
    const float* __restrict__ Wf, const float* __restrict__ Wb,
    const float* __restrict__ bf, const float* __restrict__ bb,
    float* __restrict__ outf, float* __restrict__ outb) {
  int bx = blockIdx.x;   // N tile (0..7)
  int by = blockIdx.y;   // M tile (0..15)
  int dir = blockIdx.z;
  const float* W = dir ? Wb : Wf;
  const float* bias = dir ? bb : bf;
  float* out = dir ? outb : outf;

  __shared__ __align__(16) float Xs[16][132];
  __shared__ __align__(16) float Ws[16][132];

  int tid = threadIdx.x;
  int tx = tid & 15;   // 0..15 -> N
  int ty = tid >> 4;   // 0..15 -> M

  float acc[8][8];
#pragma unroll
  for (int i = 0; i < 8; i++)
#pragma unroll
    for (int j = 0; j < 8; j++) acc[i][j] = 0.0f;

  for (int kt = 0; kt < DMODEL / 16; kt++) {
    __syncthreads();
#pragma unroll
    for (int l = 0; l < 2; l++) {
      int fi = tid + l * 256;        // 0..511  (128 rows x 4 float4)
      int row = fi >> 2;
      int kq = fi & 3;
      float4 xv = *(const float4*)(X + (size_t)(by * 128 + row) * DMODEL + kt * 16 + kq * 4);
      Xs[kq * 4 + 0][row] = xv.x;
      Xs[kq * 4 + 1][row] = xv.y;
      Xs[kq * 4 + 2][row] = xv.z;
      Xs[kq * 4 + 3][row] = xv.w;
      float4 wv = *(const float4*)(W + (size_t)(bx * 128 + row) * DMODEL + kt * 16 + kq * 4);
      Ws[kq * 4 + 0][row] = wv.x;
      Ws[kq * 4 + 1][row] = wv.y;
      Ws[kq * 4 + 2][row] = wv.z;
      Ws[kq * 4 + 3][row] = wv.w;
    }
    __syncthreads();
#pragma unroll
    for (int k = 0; k < 16; k++) {
      float4 a0 = *(const float4*)&Xs[k][ty * 4];
      float4 a1 = *(const float4*)&Xs[k][64 + ty * 4];
      float4 b0 = *(const float4*)&Ws[k][tx * 4];
      float4 b1 = *(const float4*)&Ws[k][64 + tx * 4];
      float a[8] = {a0.x, a0.y, a0.z, a0.w, a1.x, a1.y, a1.z, a1.w};
      float b[8] = {b0.x, b0.y, b0.z, b0.w, b1.x, b1.y, b1.z, b1.w};
#pragma unroll
      for (int i = 0; i < 8; i++)
#pragma unroll
        for (int j = 0; j < 8; j++) acc[i][j] += a[i] * b[j];
    }
  }

  float4 bv0 = *(const float4*)(bias + bx * 128 + tx * 4);
  float4 bv1 = *(const float4*)(bias + bx * 128 + 64 + tx * 4);
  float bb8[8] = {bv0.x, bv0.y, bv0.z, bv0.w, bv1.x, bv1.y, bv1.z, bv1.w};
#pragma unroll
  for (int i = 0; i < 8; i++) {
    int row = by * 128 + ((i < 4) ? (ty * 4 + i) : (64 + ty * 4 + (i - 4)));
    float4 o0 = {acc[i][0] + bb8[0], acc[i][1] + bb8[1], acc[i][2] + bb8[2], acc[i][3] + bb8[3]};
    float4 o1 = {acc[i][4] + bb8[4], acc[i][5] + bb8[5], acc[i][6] + bb8[6], acc[i][7] + bb8[7]};
    *(float4*)(out + (size_t)row * 1024 + bx * 128 + tx * 4) = o0;
    *(float4*)(out + (size_t)row * 1024 + bx * 128 + 64 + tx * 4) = o1;
  }
}

// ---------------------------------------------------------------------------
// 3/5. Recurrence. grid: (NCAND=128 candidates, 2 dirs), block 256.
// a) Election: every WG publishes (ticket -> xcd) via agent atomics; all WGs
//    deterministically pick the first XCD with >=8 candidates (pigeonhole
//    over 128/8 guarantees one); first 8 tickets there own chunks 0..7.
// b) Probe: octet tests producer-store -> rd_l2 visibility with a BOUNDED
//    spin; votes exchanged over the proven agent path; use_l2 = all passed.
// c) Steady state (per step): FMA -> shfl reduce -> zbuf -> sync -> gates
//    (tid<32) -> publish (tag<<32|h_bits): pub_l2/rd_l2 if use_l2 else
//    relaxed agent atomics (R4) -> hbuf in LDS -> sync. Parity double-buffer.
// __launch_bounds__(256, 1): 4 waves on 4 SIMDs -> 1 wave/SIMD -> VGPR cap
// 512; Wv[32] (128 VGPRs) stays register-resident (R6 spilled at cap 128).
// ---------------------------------------------------------------------------
__global__ __launch_bounds__(256, 1) void recur_k(
    const float* __restrict__ xg_f, const float* __restrict__ xg_b,
    const float* __restrict__ Whh_f, const float* __restrict__ Whh_b,
    const float* __restrict__ bhh_f, const float* __restrict__ bhh_b,
    float* __restrict__ xnext, unsigned long long* __restrict__ hcomm_base,
    int* __restrict__ elect_base, unsigned long long* __restrict__ probe_base,
    int* __restrict__ vote_base) {
  int dir = blockIdx.y;         // 0=f, 1=b
  int tid = threadIdx.x;        // 0..255

  // ---- a) election -------------------------------------------------------
  int xcd;
  asm volatile("s_getreg_b32 %0, hwreg(HW_REG_XCC_ID)" : "=s"(xcd));
  xcd &= 7;
  int* cnt = elect_base + dir * (1 + NCAND);
  int* tab = cnt + 1;

  __shared__ int e_tab[NCAND];
  __shared__ int e_info[4];   // [0]=ticket, [1]=sel, [2]=kc, [3]=use_l2
  __shared__ int probe_ok[8];
  if (tid == 0) {
    int ticket = __hip_atomic_fetch_add(cnt, 1, __ATOMIC_RELAXED,
                                        __HIP_MEMORY_SCOPE_AGENT);
    __hip_atomic_store(&tab[ticket], xcd + 1, __ATOMIC_RELAXED,
                       __HIP_MEMORY_SCOPE_AGENT);
    e_info[0] = ticket;
  }
  if (tid < NCAND) {
    int v;
    do {
      v = __hip_atomic_load(&tab[tid], __ATOMIC_RELAXED,
                            __HIP_MEMORY_SCOPE_AGENT);
    } while (v == 0);
    e_tab[tid] = v - 1;
  }
  __syncthreads();
  if (tid == 0) {
    int ticket = e_info[0];
    int counts[8] = {0, 0, 0, 0, 0, 0, 0, 0};
    int home = -1;
    for (int i = 0; i < NCAND; i++) {
      int x = e_tab[i];
      counts[x]++;
      if (counts[x] == 8 && home < 0) home = x;
    }
    int sel = 0, kc = 0, probe = 0;
    if (home >= 0) {
      if (xcd == home) {
        int rank = 0;
        for (int i = 0; i < ticket; i++)
          if (e_tab[i] == home) rank++;
        if (rank < 8) { sel = 1; kc = rank; probe = 1; }
      }
    } else {
      if (ticket < 8) { sel = 1; kc = ticket; probe = 0; }
    }
    e_info[1] = sel; e_info[2] = kc; e_info[3] = probe;
  }
  __syncthreads();
  if (!e_info[1]) return;      // not selected: exit before loading weights
  int kc = e_info[2];
  int do_probe = e_info[3];
  int use_l2 = 0;

  // ---- b) coherence probe (bounded; decision via proven agent path) ------
  if (do_probe) {
    unsigned long long* probe = probe_base + (size_t)dir * 8 * 16;  // 128B/slot
    int* vote = vote_base + dir * 8;
    if (tid == 0) {
      pub_l2(&probe[kc * 16], 0xBEEF000000000000ull + (unsigned)kc);
    }
    if (tid < 8) {
      int found = 0;
      for (int iter = 0; iter < 3000 && !found; ++iter) {
        if (rd_l2(&probe[tid * 16]) ==
            0xBEEF000000000000ull + (unsigned)tid) found = 1;
      }
      probe_ok[tid] = found;
    }
    __syncthreads();
    if (tid == 0) {
      int ok = 1;
      for (int i = 0; i < 8; i++) ok &= probe_ok[i];
      // publish vote (1=fail, 2=pass) over the RELIABLE agent path
      __hip_atomic_store(&vote[kc], 1 + ok, __ATOMIC_RELAXED,
                         __HIP_MEMORY_SCOPE_AGENT);
    }
    if (tid < 8) {
      int v;
      do {
        v = __hip_atomic_load(&vote[tid], __ATOMIC_RELAXED,
                              __HIP_MEMORY_SCOPE_AGENT);
      } while (v == 0);   // bounded publishers => terminates
      probe_ok[tid] = v;
    }
    __syncthreads();
    if (tid == 0) {
      int all2 = 1;
      for (int i = 0; i < 8; i++) all2 &= (probe_ok[i] == 2);
      e_info[3] = all2;
    }
    __syncthreads();
    use_l2 = e_info[3];
  }

  // ---- c) setup ----------------------------------------------------------
  const float* Whh = dir ? Whh_b : Whh_f;
  const float* bhh = dir ? bhh_b : bhh_f;
  const float* xg = dir ? xg_b : xg_f;
  unsigned long long* hcomm = hcomm_base + (size_t)dir * 2 * HD;

  int r = tid >> 1;             // local row 0..127
  int half = tid & 1;           // which 128-col half
  int g = r >> 5;               // gate 0..3 (i,f,g,o)
  int kl = r & 31;
  int grow = g * 256 + kc * 32 + kl;  // global gate row 0..1023

  float4 Wv[32];
  const float4* wrow = (const float4*)(Whh + (size_t)grow * HD + half * 128);
#pragma unroll
  for (int j = 0; j < 32; j++) Wv[j] = wrow[j];
  float bias = bhh[grow];

  __shared__ __align__(16) float hbuf[HD];   // h_{t-1}
  __shared__ float zbuf[128];
  hbuf[tid] = 0.0f;
  __syncthreads();

  float c = 0.0f;               // cell state, used by tid<32
  bool is_remote = ((tid >> 5) != kc);  // this thread polls entry `tid`

#pragma unroll 1
  for (int it = 0; it < T_LEN; ++it) {
    int t = dir ? (T_LEN - 1 - it) : it;
    int p = it & 1;
    unsigned int tag = (unsigned)(it + 1);

    // prefetch xg early (even lanes only; consumed after the FMA loop)
    float xgv = 0.0f;
    if (!half) xgv = xg[(size_t)t * 1024 + grow];

    const float4* h4 = (const float4*)hbuf + half * 32;
    float4 acc = {0.f, 0.f, 0.f, 0.f};
#pragma unroll
    for (int j = 0; j < 32; j++) {
      float4 hv = h4[j];
      acc.x += Wv[j].x * hv.x;
      acc.y += Wv[j].y * hv.y;
      acc.z += Wv[j].z * hv.z;
      acc.w += Wv[j].w * hv.w;
    }
    float s = (acc.x + acc.y) + (acc.z + acc.w);
    s += __shfl_xor(s, 1, 64);   // combine the two halves of the row
    if (!half) zbuf[r] = s + xgv + bias;
    __syncthreads();             // zbuf ready; hbuf reads of h_{t-1} done

    if (tid < 32) {
      float zi = zbuf[tid];
      float zf = zbuf[32 + tid];
      float zg = zbuf[64 + tid];
      float zo = zbuf[96 + tid];
      c = fsig(zf) * c + fsig(zi) * ftanh(zg);
      float h = fsig(zo) * ftanh(c);
      union { float f; unsigned u; } cv;
      cv.f = h;
      unsigned long long pkt = ((unsigned long long)tag << 32) | cv.u;
      // publish FIRST (critical path), then feed next pipeline stage
      if (use_l2) {
        pub_l2(&hcomm[p * HD + kc * 32 + tid], pkt);
      } else {
        __hip_atomic_store(&hcomm[p * HD + kc * 32 + tid], pkt,
                           __ATOMIC_RELAXED, __HIP_MEMORY_SCOPE_AGENT);
      }
      xnext[(size_t)t * DMODEL + dir * HD + kc * 32 + tid] = h;
      hbuf[kc * 32 + tid] = h;
    }
    if (is_remote) {
      unsigned long long v;
      if (use_l2) {
        do { v = rd_l2(&hcomm[p * HD + tid]); } while ((unsigned)(v >> 32) != tag);
      } else {
        do {
          v = __hip_atomic_load(&hcomm[p * HD + tid], __ATOMIC_RELAXED,
                                __HIP_MEMORY_SCOPE_AGENT);
        } while ((unsigned)(v >> 32) != tag);
      }
      union { unsigned u; float f; } cv;
      cv.u = (unsigned)v;
      hbuf[tid] = cv.f;
    }
    __syncthreads();             // full h_t assembled in LDS
  }
}

// ---------------------------------------------------------------------------
// 6. Projection: feats[t][n] = x2[t][:] . W_out[n][:] + b_out[n]
// ---------------------------------------------------------------------------
__global__ void proj_k(const float* __restrict__ x2,
                       const float* __restrict__ Wo,
                       const float* __restrict__ bo,
                       float* __restrict__ feats) {
  int t = blockIdx.x;
  int tid = threadIdx.x;
  int n = tid & 31;
  int seg = tid >> 5;   // 0..7
  __shared__ float red[8][32];
  float s = 0.0f;
  if (n < NTAGS) {
    const float* xr = x2 + (size_t)t * DMODEL + seg * 64;
    const float* wr = Wo + (size_t)n * DMODEL + seg * 64;
#pragma unroll
    for (int j = 0; j < 64; j++) s += xr[j] * wr[j];
  }
  red[seg][n] = s;
  __syncthreads();
  if (tid < NTAGS) {
    float tot = bo[tid];
#pragma unroll
    for (int k = 0; k < 8; k++) tot += red[k][tid];
    feats[(size_t)t * NTAGS + tid] = tot;
  }
}

// ---------------------------------------------------------------------------
// 7. Viterbi: single block, 64 threads (one wave).
// ---------------------------------------------------------------------------
__global__ void viterbi_k(const float* __restrict__ feats,
                          const float* __restrict__ tr,
                          float* __restrict__ out) {
  __shared__ float v[NTAGS];
  __shared__ unsigned char bp[T_LEN * NTAGS];  // 40KB
  __shared__ float term[NTAGS];
  int tid = threadIdx.x;

  float trrow[NTAGS];
  if (tid < NTAGS) {
#pragma unroll
    for (int p = 0; p < NTAGS; p++) trrow[p] = tr[tid * NTAGS + p];
    v[tid] = (tid == START_TAG) ? 0.0f : -10000.0f;
  }
  __syncthreads();

#pragma unroll 1
  for (int t = 0; t < T_LEN; t++) {
    float fv = 0.0f;
    if (tid < NTAGS) fv = feats[(size_t)t * NTAGS + tid];
    float best = -3.4e38f;
    int arg = 0;
    if (tid < NTAGS) {
#pragma unroll
      for (int p = 0; p < NTAGS; p++) {
        float sc = v[p] + trrow[p];
        if (sc > best) { best = sc; arg = p; }
      }
      bp[t * NTAGS + tid] = (unsigned char)arg;
    }
    __syncthreads();
    if (tid < NTAGS) v[tid] = best + fv;
    __syncthreads();
  }

  if (tid < NTAGS) term[tid] = v[tid] + tr[END_TAG * NTAGS + tid];
  __syncthreads();
  if (tid == 0) {
    float bs = term[0];
    int bi = 0;
    for (int p = 1; p < NTAGS; p++) {
      if (term[p] > bs) { bs = term[p]; bi = p; }
    }
    out[0] = bs;
    int tag = bi;
    for (int t = T_LEN - 1; t >= 0; t--) {
      out[1 + t] = (float)tag;
      tag = bp[t * NTAGS + tag];
    }
  }
}

// ---------------------------------------------------------------------------
// Launch
// ---------------------------------------------------------------------------
extern "C" void kernel_launch(void* const* d_in, const int* in_sizes, int n_in,
                              void* d_out, int out_size, void* d_ws, size_t ws_size,
                              hipStream_t stream) {
  const int* sent = (const int*)d_in[0];
  const float* emb = (const float*)d_in[1];
  const float* l0f_Wih = (const float*)d_in[2];
  const float* l0f_Whh = (const float*)d_in[3];
  const float* l0f_bih = (const float*)d_in[4];
  const float* l0f_bhh = (const float*)d_in[5];
  const float* l0b_Wih = (const float*)d_in[6];
  const float* l0b_Whh = (const float*)d_in[7];
  const float* l0b_bih = (const float*)d_in[8];
  const float* l0b_bhh = (const float*)d_in[9];
  const float* l1f_Wih = (const float*)d_in[10];
  const float* l1f_Whh = (const float*)d_in[11];
  const float* l1f_bih = (const float*)d_in[12];
  const float* l1f_bhh = (const float*)d_in[13];
  const float* l1b_Wih = (const float*)d_in[14];
  const float* l1b_Whh = (const float*)d_in[15];
  const float* l1b_bih = (const float*)d_in[16];
  const float* l1b_bhh = (const float*)d_in[17];
  const float* W_out = (const float*)d_in[18];
  const float* b_out = (const float*)d_in[19];
  const float* transitions = (const float*)d_in[20];

  char* ws = (char*)d_ws;
  size_t off = 0;
  float* x0 = (float*)(ws + off);  off += (size_t)T_LEN * DMODEL * 4;          // 4MB
  float* xgf = (float*)(ws + off); off += (size_t)T_LEN * 1024 * 4;            // 8MB
  float* xgb = (float*)(ws + off); off += (size_t)T_LEN * 1024 * 4;            // 8MB
  float* x1 = (float*)(ws + off);  off += (size_t)T_LEN * DMODEL * 4;          // 4MB
  float* x2 = (float*)(ws + off);  off += (size_t)T_LEN * DMODEL * 4;          // 4MB
  float* feats = (float*)(ws + off); off += (size_t)T_LEN * NTAGS * 4;

  // sync area (single contiguous memset)
  off = (off + 127) & ~(size_t)127;
  char* sync_area = ws + off;
  unsigned long long* hcomm0 = (unsigned long long*)(sync_area);          // 8KB
  unsigned long long* hcomm1 = (unsigned long long*)(sync_area + 8192);   // 8KB
  int* elect0 = (int*)(sync_area + 16384);                                // 2KB
  int* elect1 = (int*)(sync_area + 18432);                                // 2KB
  unsigned long long* probe0 = (unsigned long long*)(sync_area + 20480);  // 2KB
  unsigned long long* probe1 = (unsigned long long*)(sync_area + 22528);  // 2KB
  int* vote0 = (int*)(sync_area + 24576);                                 // 1KB
  int* vote1 = (int*)(sync_area + 25600);                                 // 1KB
  size_t sync_bytes = 26624;
  off += sync_bytes;

  float* outf = (float*)d_out;

  // zero all sync state (d_ws is re-poisoned to 0xAA before every launch)
  (void)hipMemsetAsync(sync_area, 0, sync_bytes, stream);

  embed_k<<<dim3(T_LEN), dim3(128), 0, stream>>>(sent, emb, x0);

  gemm_xg_k<<<dim3(8, 16, 2), dim3(256), 0, stream>>>(
      x0, l0f_Wih, l0b_Wih, l0f_bih, l0b_bih, xgf, xgb);

  recur_k<<<dim3(NCAND, 2), dim3(256), 0, stream>>>(
      xgf, xgb, l0f_Whh, l0b_Whh, l0f_bhh, l0b_bhh, x1, hcomm0, elect0,
      probe0, vote0);

  gemm_xg_k<<<dim3(8, 16, 2), dim3(256), 0, stream>>>(
      x1, l1f_Wih, l1b_Wih, l1f_bih, l1b_bih, xgf, xgb);

  recur_k<<<dim3(NCAND, 2), dim3(256), 0, stream>>>(
      xgf, xgb, l1f_Whh, l1b_Whh, l1f_bhh, l1b_bhh, x2, hcomm1, elect1,
      probe1, vote1);

  proj_k<<<dim3(T_LEN), dim3(256), 0, stream>>>(x2, W_out, b_out, feats);

  viterbi_k<<<dim3(1), dim3(64), 0, stream>>>(feats, transitions, outf);
}